// Round 1
// baseline (34601.859 us; speedup 1.0000x reference)
//
#include <hip/hip_runtime.h>
#include <hip/hip_bf16.h>

// LSTM (B=64,T=512,I=512,H=1024,O=1), 2 layers + sigmoid head.
// Design: per-layer cooperative kernel, 256 WGs x 256 thr. Each WG owns 4
// hidden units (16 gate rows i,f,g,o x 4 units), W_ih/W_hh slices resident in
// LDS (XOR-swizzled) for all 512 steps. Per step: fused input GEMM + recurrent
// GEMM via mfma_f32_16x16x32_bf16 (wave w = batch tile w*16..w*16+15), fp32
// accum, shuffle-redistribute gates, per-thread c-state in a register,
// custom device-scope grid barrier per step.

namespace {

constexpr int B_ = 64, T_ = 512, I_ = 512, H_ = 1024;

typedef __attribute__((ext_vector_type(8))) short short8;
typedef __attribute__((ext_vector_type(4))) float f32x4;

__device__ __forceinline__ float sigm(float x)  { return 1.f / (1.f + __expf(-x)); }
__device__ __forceinline__ float tanhx(float x) { return 2.f / (1.f + __expf(-2.f * x)) - 1.f; }

// RNE float->bf16 (bit-level, no dependence on __hip_bfloat16 internals)
__device__ __forceinline__ unsigned short f2bf(float f) {
  unsigned u = __float_as_uint(f);
  unsigned rnd = 0x7FFFu + ((u >> 16) & 1u);
  return (unsigned short)((u + rnd) >> 16);
}
__device__ __forceinline__ float bf2f(unsigned short s) {
  return __uint_as_float(((unsigned)s) << 16);
}

__global__ void cvt_bf16_k(const float* __restrict__ src, unsigned short* __restrict__ dst, int n4) {
  int i = blockIdx.x * 256 + threadIdx.x;
  if (i >= n4) return;
  float4 v = reinterpret_cast<const float4*>(src)[i];
  ushort4 o;
  o.x = f2bf(v.x); o.y = f2bf(v.y); o.z = f2bf(v.z); o.w = f2bf(v.w);
  reinterpret_cast<ushort4*>(dst)[i] = o;
}

__global__ void zero_init_k(unsigned short* __restrict__ h1, unsigned short* __restrict__ h2,
                            unsigned* __restrict__ bar) {
  int i = blockIdx.x * 256 + threadIdx.x;
  if (i < B_ * H_) h1[i] = 0;           // h1 slab 0 (t=-1 state)
  if (i < 2 * B_ * H_) h2[i] = 0;       // h2 ping-pong slabs
  if (i == 0) { bar[0] = 0; bar[1] = 0; }
}

// K_IN: input width (512 for layer 0, 1024 for layer 1).
// in strides are in elements. hout: [slabs][B][H] bf16; read slab = t&wr_mask,
// write slab = (t+1)&wr_mask. Layer0: wr_mask=1023 (full record, 513 slabs).
// Layer1: wr_mask=1 (ping-pong, final h at slab 0 since T even).
template<int K_IN>
__global__ __launch_bounds__(256, 2) void lstm_layer(
    const unsigned short* __restrict__ in, size_t in_stride_t, size_t in_stride_b,
    const unsigned short* __restrict__ w_in,   // [4H][K_IN] bf16
    const unsigned short* __restrict__ w_hh,   // [4H][H] bf16
    const float* __restrict__ b_ih, const float* __restrict__ b_hh,
    unsigned short* __restrict__ hout, int wr_mask,
    unsigned* bar_cnt, unsigned* bar_gen)
{
  __shared__ unsigned short s_win[16 * K_IN];
  __shared__ unsigned short s_whh[16 * H_];

  const int tid  = threadIdx.x;
  const int wg   = blockIdx.x;      // 0..255
  const int wave = tid >> 6;        // 0..3 -> batch tile
  const int lane = tid & 63;
  const int j0   = wg * 4;          // first hidden unit owned by this WG
  const int n    = lane & 15;       // gate-row (D column) this lane covers

  // ---- stage W slices into LDS with XOR swizzle (shorts: k ^= (r&7)<<3) ----
  constexpr int CH_IN = K_IN / 8;
  for (int c = tid; c < 16 * CH_IN; c += 256) {
    int r = c / CH_IN;
    int kc = (c % CH_IN) * 8;
    int grow = (r >> 2) * H_ + j0 + (r & 3);
    *reinterpret_cast<short8*>(&s_win[r * K_IN + (kc ^ ((r & 7) << 3))]) =
        *reinterpret_cast<const short8*>(&w_in[(size_t)grow * K_IN + kc]);
  }
  constexpr int CH_HH = H_ / 8;
  for (int c = tid; c < 16 * CH_HH; c += 256) {
    int r = c / CH_HH;
    int kc = (c % CH_HH) * 8;
    int grow = (r >> 2) * H_ + j0 + (r & 3);
    *reinterpret_cast<short8*>(&s_whh[r * H_ + (kc ^ ((r & 7) << 3))]) =
        *reinterpret_cast<const short8*>(&w_hh[(size_t)grow * H_ + kc]);
  }
  const int grow_n = (n >> 2) * H_ + j0 + (n & 3);
  const float bias_n = b_ih[grow_n] + b_hh[grow_n];
  __syncthreads();

  // ---- per-lane MFMA addressing ----
  const int k0   = (lane >> 4) * 8;       // k offset within 32-wide K tile
  const int arow = wave * 16 + n;         // batch row this lane loads (A frag)
  const int swz_n = (n & 7) << 3;
  // ---- elementwise identity: one thread per (batch, unit) ----
  const int eb = wave * 16 + (lane >> 2); // global batch 0..63
  const int eu = lane & 3;                // unit 0..3
  float cst = 0.f;                        // c-state lives here for all 512 steps

  const unsigned short* a_in_base = in + (size_t)arow * in_stride_b + k0;
  const unsigned short* h_base    = hout + (size_t)arow * H_ + k0;
  unsigned short* w_ptr           = hout + (size_t)eb * H_ + j0 + eu;

  for (int t = 0; t < T_; ++t) {
    f32x4 acc = {0.f, 0.f, 0.f, 0.f};

    // fused input GEMM: x[t] (or h1[t]) @ W_in^T
    const unsigned short* a_in = a_in_base + (size_t)t * in_stride_t;
    #pragma unroll 8
    for (int kk = 0; kk < K_IN / 32; ++kk) {
      short8 av = *reinterpret_cast<const short8*>(a_in + kk * 32);
      short8 bv = *reinterpret_cast<const short8*>(&s_win[n * K_IN + ((k0 + kk * 32) ^ swz_n)]);
      acc = __builtin_amdgcn_mfma_f32_16x16x32_bf16(av, bv, acc, 0, 0, 0);
    }
    // recurrent GEMM: h_prev @ W_hh^T
    const unsigned short* a_h = h_base + (size_t)(t & wr_mask) * (B_ * H_);
    #pragma unroll 8
    for (int kk = 0; kk < H_ / 32; ++kk) {
      short8 av = *reinterpret_cast<const short8*>(a_h + kk * 32);
      short8 bv = *reinterpret_cast<const short8*>(&s_whh[n * H_ + ((k0 + kk * 32) ^ swz_n)]);
      acc = __builtin_amdgcn_mfma_f32_16x16x32_bf16(av, bv, acc, 0, 0, 0);
    }
    acc[0] += bias_n; acc[1] += bias_n; acc[2] += bias_n; acc[3] += bias_n;

    // D layout: lane holds P[m=(lane>>4)*4+r][n=lane&15]. Redistribute so lane
    // t owns (b_local=t>>2, u=t&3) with all 4 gates: source lane for P[m][4g+u]
    // is (t&48)|(g<<2)|(t&3), register m&3 = (t>>2)&3.
    const int rsel  = (lane >> 2) & 3;
    const int sbase = (lane & 48) | (lane & 3);
    float pg[4];
    #pragma unroll
    for (int g = 0; g < 4; ++g) {
      int src = sbase | (g << 2);
      float t0 = __shfl(acc[0], src, 64);
      float t1 = __shfl(acc[1], src, 64);
      float t2 = __shfl(acc[2], src, 64);
      float t3 = __shfl(acc[3], src, 64);
      pg[g] = (rsel == 0) ? t0 : (rsel == 1) ? t1 : (rsel == 2) ? t2 : t3;
    }
    float gi = sigm(pg[0]);
    float gf = sigm(pg[1]);
    float gg = tanhx(pg[2]);
    float go = sigm(pg[3]);
    cst = gf * cst + gi * gg;
    float hv = go * tanhx(cst);
    w_ptr[(size_t)((t + 1) & wr_mask) * (B_ * H_)] = f2bf(hv);

    // ---- grid barrier (gen/count, device scope) ----
    __syncthreads();
    if (tid == 0) {
      __threadfence();  // release h writes to agent scope (cross-XCD)
      unsigned g0 = __hip_atomic_load(bar_gen, __ATOMIC_RELAXED, __HIP_MEMORY_SCOPE_AGENT);
      unsigned a0 = __hip_atomic_fetch_add(bar_cnt, 1u, __ATOMIC_ACQ_REL, __HIP_MEMORY_SCOPE_AGENT);
      if (a0 == gridDim.x - 1) {
        __hip_atomic_store(bar_cnt, 0u, __ATOMIC_RELAXED, __HIP_MEMORY_SCOPE_AGENT);
        __hip_atomic_fetch_add(bar_gen, 1u, __ATOMIC_RELEASE, __HIP_MEMORY_SCOPE_AGENT);
      } else {
        while (__hip_atomic_load(bar_gen, __ATOMIC_ACQUIRE, __HIP_MEMORY_SCOPE_AGENT) == g0) {
          __builtin_amdgcn_s_sleep(2);
        }
      }
      __threadfence();  // acquire: invalidate stale cached h
    }
    __syncthreads();
  }
}

__global__ void out_head(const unsigned short* __restrict__ h2,
                         const float* __restrict__ W_out,
                         const float* __restrict__ b_out,
                         float* __restrict__ out) {
  int b = blockIdx.x;      // 64
  int lane = threadIdx.x;  // 64 (one wave)
  float s = 0.f;
  for (int k = lane; k < H_; k += 64)
    s += bf2f(h2[(size_t)b * H_ + k]) * W_out[k];
  #pragma unroll
  for (int off = 32; off; off >>= 1) s += __shfl_down(s, off, 64);
  if (lane == 0) out[b] = sigm(s + b_out[0]);
}

} // namespace

extern "C" void kernel_launch(void* const* d_in, const int* in_sizes, int n_in,
                              void* d_out, int out_size, void* d_ws, size_t ws_size,
                              hipStream_t stream) {
  const float* x    = (const float*)d_in[0];
  const float* Wih0 = (const float*)d_in[1];
  const float* Whh0 = (const float*)d_in[2];
  const float* bih0 = (const float*)d_in[3];
  const float* bhh0 = (const float*)d_in[4];
  const float* Wih1 = (const float*)d_in[5];
  const float* Whh1 = (const float*)d_in[6];
  const float* bih1 = (const float*)d_in[7];
  const float* bhh1 = (const float*)d_in[8];
  const float* Wout = (const float*)d_in[9];
  const float* bout = (const float*)d_in[10];
  float* out = (float*)d_out;

  // workspace layout (~131 MB)
  char* ws = (char*)d_ws;
  size_t off = 0;
  auto alloc = [&](size_t bytes) -> char* {
    char* p = ws + off;
    off += (bytes + 255) & ~(size_t)255;
    return p;
  };
  unsigned* bar        = (unsigned*)alloc(256);
  unsigned short* xb   = (unsigned short*)alloc((size_t)B_ * T_ * I_ * 2);
  unsigned short* wih0 = (unsigned short*)alloc((size_t)4 * H_ * I_ * 2);
  unsigned short* whh0 = (unsigned short*)alloc((size_t)4 * H_ * H_ * 2);
  unsigned short* wih1 = (unsigned short*)alloc((size_t)4 * H_ * H_ * 2);
  unsigned short* whh1 = (unsigned short*)alloc((size_t)4 * H_ * H_ * 2);
  unsigned short* h1   = (unsigned short*)alloc((size_t)(T_ + 1) * B_ * H_ * 2);
  unsigned short* h2   = (unsigned short*)alloc((size_t)2 * B_ * H_ * 2);

  auto cvt = [&](const float* s, unsigned short* d, int nelem) {
    int n4 = nelem / 4;
    cvt_bf16_k<<<(n4 + 255) / 256, 256, 0, stream>>>(s, d, n4);
  };
  cvt(x,    xb,   B_ * T_ * I_);
  cvt(Wih0, wih0, 4 * H_ * I_);
  cvt(Whh0, whh0, 4 * H_ * H_);
  cvt(Wih1, wih1, 4 * H_ * H_);
  cvt(Whh1, whh1, 4 * H_ * H_);
  zero_init_k<<<(2 * B_ * H_ + 255) / 256, 256, 0, stream>>>(h1, h2, bar);

  // layer 0: input x [B][T][I] (stride_t = I, stride_b = T*I), full h1 record
  lstm_layer<I_><<<256, 256, 0, stream>>>(
      xb, (size_t)I_, (size_t)T_ * I_,
      wih0, whh0, bih0, bhh0, h1, 1023, bar, bar + 1);

  // layer 1: input h1 slabs 1..512 ([t][b][k]: stride_t = B*H, stride_b = H),
  // h2 ping-pong (final h at slab 0)
  lstm_layer<H_><<<256, 256, 0, stream>>>(
      h1 + B_ * H_, (size_t)B_ * H_, (size_t)H_,
      wih1, whh1, bih1, bhh1, h2, 1, bar, bar + 1);

  out_head<<<B_, 64, 0, stream>>>(h2, Wout, bout, out);
}

// Round 2
// 13556.906 us; speedup vs baseline: 2.5523x; 2.5523x over previous
//
#include <hip/hip_runtime.h>
#include <hip/hip_bf16.h>

// LSTM (B=64,T=512,I=512,H=1024,O=1), 2 layers + sigmoid head.
// R2: latency-bound fix. Coherence protocol redesigned:
//  - h written via agent-scope RELAXED atomic u64 stores (write-through to L3,
//    no dirty L2 -> no release fence needed; __syncthreads drains vmcnt).
//  - h read via plain cached b128 loads (L2-shared within XCD) after ONE
//    agent acquire fence per step (single buffer_inv, not one per poll!).
//  - Spin polls with RELAXED atomic load + s_sleep(1).
//  - Two-level arrival: 8 group counters -> 1 global counter (monotonic).
//  - Input GEMM (x-based, barrier-independent) runs BEFORE the wait, hiding
//    WG skew + barrier propagation.

namespace {

constexpr int B_ = 64, T_ = 512, I_ = 512, H_ = 1024;

typedef __attribute__((ext_vector_type(8))) short short8;
typedef __attribute__((ext_vector_type(4))) float f32x4;

__device__ __forceinline__ float sigm(float x)  { return 1.f / (1.f + __expf(-x)); }
__device__ __forceinline__ float tanhx(float x) { return 2.f / (1.f + __expf(-2.f * x)) - 1.f; }

__device__ __forceinline__ unsigned f2bf(float f) {
  unsigned u = __float_as_uint(f);
  unsigned rnd = 0x7FFFu + ((u >> 16) & 1u);
  return (u + rnd) >> 16;   // low 16 bits valid
}
__device__ __forceinline__ float bf2f(unsigned short s) {
  return __uint_as_float(((unsigned)s) << 16);
}

__global__ void cvt_bf16_k(const float* __restrict__ src, unsigned short* __restrict__ dst, int n4) {
  int i = blockIdx.x * 256 + threadIdx.x;
  if (i >= n4) return;
  float4 v = reinterpret_cast<const float4*>(src)[i];
  ushort4 o;
  o.x = (unsigned short)f2bf(v.x); o.y = (unsigned short)f2bf(v.y);
  o.z = (unsigned short)f2bf(v.z); o.w = (unsigned short)f2bf(v.w);
  reinterpret_cast<ushort4*>(dst)[i] = o;
}

__global__ void zero_init_k(unsigned short* __restrict__ h1, unsigned short* __restrict__ h2,
                            unsigned* __restrict__ bar) {
  int i = blockIdx.x * 256 + threadIdx.x;
  if (i < B_ * H_) h1[i] = 0;           // h1 slab 0 (t=-1 state)
  if (i < 2 * B_ * H_) h2[i] = 0;       // h2 ping-pong slabs
  if (i < 1024) bar[i] = 0;             // both layers' barrier counters
}

// Barrier region layout per layer (512 u32 = 2KB): glob at [0] (own line),
// group g counter at [64 + 32*g] (8 groups of 32 WGs, separate 128B lines).
//
// hout: [slabs][B][H] bf16; read slab t&wr_mask, write slab (t+1)&wr_mask.
// Layer0: wr_mask=1023 (full record). Layer1: wr_mask=1 (ping-pong).
template<int K_IN>
__global__ __launch_bounds__(256, 2) void lstm_layer(
    const unsigned short* __restrict__ in, size_t in_stride_t, size_t in_stride_b,
    const unsigned short* __restrict__ w_in,   // [4H][K_IN] bf16
    const unsigned short* __restrict__ w_hh,   // [4H][H] bf16
    const float* __restrict__ b_ih, const float* __restrict__ b_hh,
    unsigned short* __restrict__ hout, int wr_mask,
    unsigned* __restrict__ bars)
{
  __shared__ unsigned short s_win[16 * K_IN];
  __shared__ unsigned short s_whh[16 * H_];

  const int tid  = threadIdx.x;
  const int wg   = blockIdx.x;      // 0..255
  const int wave = tid >> 6;        // 0..3 -> batch tile
  const int lane = tid & 63;
  const int j0   = wg * 4;          // first hidden unit owned by this WG
  const int n    = lane & 15;       // gate-row (D column) this lane covers

  unsigned* glob = bars;
  unsigned* grp  = bars + 64 + (wg >> 5) * 32;

  // ---- stage W slices into LDS with XOR swizzle (shorts: k ^= (r&7)<<3) ----
  constexpr int CH_IN = K_IN / 8;
  for (int c = tid; c < 16 * CH_IN; c += 256) {
    int r = c / CH_IN;
    int kc = (c % CH_IN) * 8;
    int grow = (r >> 2) * H_ + j0 + (r & 3);
    *reinterpret_cast<short8*>(&s_win[r * K_IN + (kc ^ ((r & 7) << 3))]) =
        *reinterpret_cast<const short8*>(&w_in[(size_t)grow * K_IN + kc]);
  }
  constexpr int CH_HH = H_ / 8;
  for (int c = tid; c < 16 * CH_HH; c += 256) {
    int r = c / CH_HH;
    int kc = (c % CH_HH) * 8;
    int grow = (r >> 2) * H_ + j0 + (r & 3);
    *reinterpret_cast<short8*>(&s_whh[r * H_ + (kc ^ ((r & 7) << 3))]) =
        *reinterpret_cast<const short8*>(&w_hh[(size_t)grow * H_ + kc]);
  }
  const int grow_n = (n >> 2) * H_ + j0 + (n & 3);
  const float bias_n = b_ih[grow_n] + b_hh[grow_n];
  __syncthreads();

  // ---- per-lane MFMA addressing ----
  const int k0   = (lane >> 4) * 8;       // k offset within 32-wide K tile
  const int arow = wave * 16 + n;         // batch row this lane loads (A frag)
  const int swz_n = (n & 7) << 3;
  // ---- elementwise identity: one thread per (batch, unit) ----
  const int eb = wave * 16 + (lane >> 2); // global batch 0..63
  const int eu = lane & 3;                // unit 0..3
  float cst = 0.f;

  const unsigned short* a_in_base = in + (size_t)arow * in_stride_b + k0;
  const unsigned short* h_base    = hout + (size_t)arow * H_ + k0;

  for (int t = 0; t < T_; ++t) {
    f32x4 acc = {0.f, 0.f, 0.f, 0.f};

    // ---- A: input GEMM (x-based, no dependence on barrier) ----
    const unsigned short* a_in = a_in_base + (size_t)t * in_stride_t;
    #pragma unroll 8
    for (int kk = 0; kk < K_IN / 32; ++kk) {
      short8 av = *reinterpret_cast<const short8*>(a_in + kk * 32);
      short8 bv = *reinterpret_cast<const short8*>(&s_win[n * K_IN + ((k0 + kk * 32) ^ swz_n)]);
      acc = __builtin_amdgcn_mfma_f32_16x16x32_bf16(av, bv, acc, 0, 0, 0);
    }

    // ---- B: wait for h[t] (all WGs' step t-1 stores at coherence point) ----
    if (t > 0) {
      if (tid == 0) {
        const unsigned tgt = (unsigned)t * 8u;
        while (__hip_atomic_load(glob, __ATOMIC_RELAXED, __HIP_MEMORY_SCOPE_AGENT) < tgt)
          __builtin_amdgcn_s_sleep(1);
      }
      __syncthreads();
      // one L1/L2 invalidate per step (NOT per poll) so cached h loads see L3
      __builtin_amdgcn_fence(__ATOMIC_ACQUIRE, "agent");
    }

    // ---- C: recurrent GEMM: h_prev @ W_hh^T (plain cached loads, L2-shared) ----
    const unsigned short* a_h = h_base + (size_t)(t & wr_mask) * (B_ * H_);
    #pragma unroll 16
    for (int kk = 0; kk < H_ / 32; ++kk) {
      short8 av = *reinterpret_cast<const short8*>(a_h + kk * 32);
      short8 bv = *reinterpret_cast<const short8*>(&s_whh[n * H_ + ((k0 + kk * 32) ^ swz_n)]);
      acc = __builtin_amdgcn_mfma_f32_16x16x32_bf16(av, bv, acc, 0, 0, 0);
    }
    acc[0] += bias_n; acc[1] += bias_n; acc[2] += bias_n; acc[3] += bias_n;

    // ---- D: redistribute gates, elementwise, coherent h store ----
    const int rsel  = (lane >> 2) & 3;
    const int sbase = (lane & 48) | (lane & 3);
    float pg[4];
    #pragma unroll
    for (int g = 0; g < 4; ++g) {
      int src = sbase | (g << 2);
      float t0 = __shfl(acc[0], src, 64);
      float t1 = __shfl(acc[1], src, 64);
      float t2 = __shfl(acc[2], src, 64);
      float t3 = __shfl(acc[3], src, 64);
      pg[g] = (rsel == 0) ? t0 : (rsel == 1) ? t1 : (rsel == 2) ? t2 : t3;
    }
    float gi = sigm(pg[0]);
    float gf = sigm(pg[1]);
    float gg = tanhx(pg[2]);
    float go = sigm(pg[3]);
    cst = gf * cst + gi * gg;
    float hv = go * tanhx(cst);

    // pack 4 units (j0..j0+3) for batch eb into one u64, write-through store
    unsigned hv16 = f2bf(hv) & 0xFFFFu;
    const int lb = lane & ~3;
    unsigned v1 = __shfl(hv16, lb | 1, 64);
    unsigned v2 = __shfl(hv16, lb | 2, 64);
    unsigned v3 = __shfl(hv16, lb | 3, 64);
    if (eu == 0) {
      unsigned long long q = (unsigned long long)(hv16 | (v1 << 16)) |
                             ((unsigned long long)(v2 | (v3 << 16)) << 32);
      unsigned long long* dst = (unsigned long long*)
          (hout + (size_t)((t + 1) & wr_mask) * (B_ * H_) + (size_t)eb * H_ + j0);
      __hip_atomic_store(dst, q, __ATOMIC_RELAXED, __HIP_MEMORY_SCOPE_AGENT);
    }

    // ---- E: arrive (2-level). __syncthreads drains all waves' vmcnt first. ----
    __syncthreads();
    if (tid == 0) {
      unsigned old = __hip_atomic_fetch_add(grp, 1u, __ATOMIC_RELAXED, __HIP_MEMORY_SCOPE_AGENT);
      if (old == (unsigned)t * 32u + 31u)
        __hip_atomic_fetch_add(glob, 1u, __ATOMIC_RELAXED, __HIP_MEMORY_SCOPE_AGENT);
    }
  }
}

__global__ void out_head(const unsigned short* __restrict__ h2,
                         const float* __restrict__ W_out,
                         const float* __restrict__ b_out,
                         float* __restrict__ out) {
  int b = blockIdx.x;      // 64
  int lane = threadIdx.x;  // 64 (one wave)
  float s = 0.f;
  for (int k = lane; k < H_; k += 64)
    s += bf2f(h2[(size_t)b * H_ + k]) * W_out[k];
  #pragma unroll
  for (int off = 32; off; off >>= 1) s += __shfl_down(s, off, 64);
  if (lane == 0) out[b] = sigm(s + b_out[0]);
}

} // namespace

extern "C" void kernel_launch(void* const* d_in, const int* in_sizes, int n_in,
                              void* d_out, int out_size, void* d_ws, size_t ws_size,
                              hipStream_t stream) {
  const float* x    = (const float*)d_in[0];
  const float* Wih0 = (const float*)d_in[1];
  const float* Whh0 = (const float*)d_in[2];
  const float* bih0 = (const float*)d_in[3];
  const float* bhh0 = (const float*)d_in[4];
  const float* Wih1 = (const float*)d_in[5];
  const float* Whh1 = (const float*)d_in[6];
  const float* bih1 = (const float*)d_in[7];
  const float* bhh1 = (const float*)d_in[8];
  const float* Wout = (const float*)d_in[9];
  const float* bout = (const float*)d_in[10];
  float* out = (float*)d_out;

  char* ws = (char*)d_ws;
  size_t off = 0;
  auto alloc = [&](size_t bytes) -> char* {
    char* p = ws + off;
    off += (bytes + 255) & ~(size_t)255;
    return p;
  };
  unsigned* bar        = (unsigned*)alloc(4096);  // 2 layers x 512 u32
  unsigned short* xb   = (unsigned short*)alloc((size_t)B_ * T_ * I_ * 2);
  unsigned short* wih0 = (unsigned short*)alloc((size_t)4 * H_ * I_ * 2);
  unsigned short* whh0 = (unsigned short*)alloc((size_t)4 * H_ * H_ * 2);
  unsigned short* wih1 = (unsigned short*)alloc((size_t)4 * H_ * H_ * 2);
  unsigned short* whh1 = (unsigned short*)alloc((size_t)4 * H_ * H_ * 2);
  unsigned short* h1   = (unsigned short*)alloc((size_t)(T_ + 1) * B_ * H_ * 2);
  unsigned short* h2   = (unsigned short*)alloc((size_t)2 * B_ * H_ * 2);

  auto cvt = [&](const float* s, unsigned short* d, int nelem) {
    int n4 = nelem / 4;
    cvt_bf16_k<<<(n4 + 255) / 256, 256, 0, stream>>>(s, d, n4);
  };
  cvt(x,    xb,   B_ * T_ * I_);
  cvt(Wih0, wih0, 4 * H_ * I_);
  cvt(Whh0, whh0, 4 * H_ * H_);
  cvt(Wih1, wih1, 4 * H_ * H_);
  cvt(Whh1, whh1, 4 * H_ * H_);
  zero_init_k<<<(2 * B_ * H_ + 255) / 256, 256, 0, stream>>>(h1, h2, bar);

  // layer 0: input x [B][T][I] (stride_t = I, stride_b = T*I), full h1 record
  lstm_layer<I_><<<256, 256, 0, stream>>>(
      xb, (size_t)I_, (size_t)T_ * I_,
      wih0, whh0, bih0, bhh0, h1, 1023, bar);

  // layer 1: input h1 slabs 1..512 ([t][b][k]: stride_t = B*H, stride_b = H),
  // h2 ping-pong (final h at slab 0 since T even)
  lstm_layer<H_><<<256, 256, 0, stream>>>(
      h1 + B_ * H_, (size_t)B_ * H_, (size_t)H_,
      wih1, whh1, bih1, bhh1, h2, 1, bar + 512);

  out_head<<<B_, 64, 0, stream>>>(h2, Wout, bout, out);
}